// Round 9
// baseline (2356.920 us; speedup 1.0000x reference)
//
#include <hip/hip_runtime.h>

#define BS    32
#define MDIM  256
#define NDIM  512
#define ITERS 1000
#define BLK   512
#define ALPHA 0.02f
#define BETA  0.02f
#define NWG   128

// R9: pipelined polling. The dependent spin (load->check->branch) samples at
// ~1 load-latency period L (~500-700cy): detection = visibility + L + U(0,L),
// and the barrier then takes the MAX over 8 waves' quantized detections —
// ~1000+cy/iter of pure sampling artifact. Fix: keep 4 outstanding
// same-address poll loads (asm: issue 4 -> s_waitcnt vmcnt(3) -> check ->
// reissue 1) -> sample period ~L/4. Same-dest clobber is benign (any
// completed value is a valid sample; mantissa tag validates the final
// drained value). sc0+sc1 on every sample -> always reads the coherence
// point (no stale-L2 class). Rate: 4x R3's = ~24 lines/cy chip-wide, under
// the ~64/cy knee where R5 died. Body = R3's verified lean loop; LDS padded
// to 86KB -> 1 wg/CU (removes R3's 2wg/CU packing confound; baseline ran
// 86KB). L2-local exchange (R7/R8) abandoned: probe-eviction false-positive
// -> stale-line pin -> deadlock class, 2 harness failures.

// ---- LDS: A-tile [32][ATS=520] + b[32]; padded to 86016B -> 1 wg/CU ----
#define ATS      520
#define BT_OFF   (32 * ATS)
#define SMEM_FL  21504                  // 86016 B

// Exchange slab: [2 parity][BS][512] floats, mantissa-tagged words (low 8
// bits = (k+1)&255): every 4B word self-validates (proven protocol).
// Agent-scope stores; poll loads go sc0+sc1 (coherence point). Tag-gating
// bounds drift <2 iters -> 2-parity overwrite safety unchanged.
#define SLAB_FL  (2 * BS * NDIM)

__device__ __forceinline__ void st_coh_u32(void* p, unsigned v) {
  __hip_atomic_store(reinterpret_cast<unsigned*>(p), v,
                     __ATOMIC_RELAXED, __HIP_MEMORY_SCOPE_AGENT);
}
__device__ __forceinline__ unsigned tagf(float v, unsigned tag) {
  return (__float_as_uint(v) & ~0xFFu) | tag;
}

// 4-deep pipelined tag-poll. Wave-uniform control flow (vcc reductions);
// exits when ALL lanes' words carry the tag. Post-exit drain + revalidate:
// in-flight same-address loads can only deliver the same tagged value
// (producer can't be 2 iters ahead: tag-gating), so the drained q is the
// consumed value; pathological mismatch re-primes.
__device__ __forceinline__ unsigned poll4(const void* p, unsigned tag) {
  unsigned q, t;
  asm volatile(
      "0:\n\t"
      "global_load_dword %[q], %[ad], off sc0 sc1\n\t"
      "global_load_dword %[q], %[ad], off sc0 sc1\n\t"
      "global_load_dword %[q], %[ad], off sc0 sc1\n\t"
      "global_load_dword %[q], %[ad], off sc0 sc1\n"
      "1:\n\t"
      "s_waitcnt vmcnt(3)\n\t"
      "v_xor_b32 %[t], %[q], %[tg]\n\t"
      "v_and_b32 %[t], 0xff, %[t]\n\t"
      "v_cmp_ne_u32 vcc, 0, %[t]\n\t"
      "s_cbranch_vccz 2f\n\t"
      "global_load_dword %[q], %[ad], off sc0 sc1\n\t"
      "s_branch 1b\n"
      "2:\n\t"
      "s_waitcnt vmcnt(0)\n\t"
      "v_xor_b32 %[t], %[q], %[tg]\n\t"
      "v_and_b32 %[t], 0xff, %[t]\n\t"
      "v_cmp_ne_u32 vcc, 0, %[t]\n\t"
      "s_cbranch_vccnz 0b"
      : [q] "=&v"(q), [t] "=&v"(t)
      : [ad] "v"(p), [tg] "v"(tag)
      : "vcc", "memory");
  return q;
}

__global__ __launch_bounds__(BLK, 1) void pdhg_kernel(
    const float* __restrict__ A, const float* __restrict__ Bvec,
    float* __restrict__ out, float* __restrict__ slab)
{
  __shared__ float smem[SMEM_FL];
  const int tid   = threadIdx.x;
  const int bid   = blockIdx.x;
  const int batch = bid & (BS - 1);      // XCD-local: a batch's 4 wgs all
  const int slice = bid >> 5;            //   share bid%8 (round-robin)
  const int lane  = tid & 63;
  const int widx  = tid >> 6;            // wave in wg, 0..7
  const int rowbase = slice * 128 + widx * 16;   // wave's 16 G-rows
  const int row_own = lane & 15;                 // lane's row (4-redundant)
  const int i_own   = rowbase + row_own;

  // ================= PROLOGUE: G rows in regs, c = A^T b (R3 verbatim) =====
  float acc[16][8];                      // acc[r][c] = G[rowbase+r][64c+lane]
#pragma unroll
  for (int r = 0; r < 16; ++r)
#pragma unroll
    for (int c = 0; c < 8; ++c) acc[r][c] = 0.f;
  float cacc = 0.f;                      // c[i_own], identical across redundant lanes

  const float* Ag = A + (size_t)batch * MDIM * NDIM;

  for (int mt = 0; mt < MDIM / 32; ++mt) {
#pragma unroll 4
    for (int q = 0; q < 8; ++q) {
      int f  = q * 512 + tid;            // float4 index in 32x512 tile
      int mm = f >> 7;
      int j  = (f & 127) << 2;
      float4 v = *reinterpret_cast<const float4*>(
          Ag + (size_t)(mt * 32 + mm) * NDIM + j);
      *reinterpret_cast<float4*>(&smem[mm * ATS + j]) = v;
    }
    if (tid < 32) smem[BT_OFF + tid] = Bvec[batch * MDIM + mt * 32 + tid];
    __syncthreads();

#pragma unroll 2
    for (int m = 0; m < 32; ++m) {
      const float* row = &smem[m * ATS];
      float4 a0 = *reinterpret_cast<const float4*>(row + rowbase);
      float4 a1 = *reinterpret_cast<const float4*>(row + rowbase + 4);
      float4 a2 = *reinterpret_cast<const float4*>(row + rowbase + 8);
      float4 a3 = *reinterpret_cast<const float4*>(row + rowbase + 12);
      float ai[16] = {a0.x,a0.y,a0.z,a0.w, a1.x,a1.y,a1.z,a1.w,
                      a2.x,a2.y,a2.z,a2.w, a3.x,a3.y,a3.z,a3.w};
      float aj[8];
#pragma unroll
      for (int c = 0; c < 8; ++c) aj[c] = row[64 * c + lane];  // 2/bank: free
      float bm  = smem[BT_OFF + m];
      float aio = row[i_own];            // broadcast within 16-lane groups
#pragma unroll
      for (int r = 0; r < 16; ++r)
#pragma unroll
        for (int c = 0; c < 8; ++c) acc[r][c] = fmaf(ai[r], aj[c], acc[r][c]);
      cacc = fmaf(aio, bm, cacc);
    }
    __syncthreads();
  }

  // ================= ITERATION ============================================
  float x = 0.f, t = 0.f;
  float*       myslot = slab + batch * NDIM + i_own;  // store (lane<16), +parity
  const float* myrd   = slab + batch * NDIM + tid;    // coalesced poll: word tid

  for (int k = 0; k < ITERS; ++k) {
    float y  = x - ALPHA * t;
    float xn = fmaxf(y - ALPHA, 0.f) - fmaxf(-y - ALPHA, 0.f);
    if (k == ITERS - 1) { x = xn; break; }

    const int      par = (k & 1) * BS * NDIM;
    const unsigned tag = (unsigned)(k + 1) & 0xFFu;
    float wv = 2.f * xn - x;
    x = xn;
    if (lane < 16) st_coh_u32(myslot + par, tagf(wv, tag));

    // 4-deep pipelined poll of this thread's word (~L/4 sample period)
    unsigned q = poll4(myrd + par, tag);

    // stage into LDS; single barrier suffices (R3 proof: a wave stores tag
    // k+1 only after its iter-k LDS reads, so passing poll k+1 implies all
    // wg-mates finished reading).
    smem[tid] = __uint_as_float(q);
    __syncthreads();

    float wr[8];
#pragma unroll
    for (int c = 0; c < 8; ++c) wr[c] = smem[64 * c + lane];  // 2/bank: free

    float S[16];
#pragma unroll
    for (int r = 0; r < 16; ++r) {
      float p = acc[r][0] * wr[0];
#pragma unroll
      for (int c = 1; c < 8; ++c) p = fmaf(acc[r][c], wr[c], p);
      S[r] = p;
    }

    // value-halving butterfly (R3-verified): after xor 1,2,4,8 lane holds
    // row (lane&15) summed over its 16-lane group; xor16+xor32 are single
    // commutative adds -> all 4 redundant lanes bit-identical.
    const bool b0 = (lane & 1), b1 = (lane & 2), b2 = (lane & 4), b3 = (lane & 8);
    float T[8];
#pragma unroll
    for (int i = 0; i < 8; ++i) {
      float keep = b0 ? S[2*i+1] : S[2*i];
      float send = b0 ? S[2*i]   : S[2*i+1];
      T[i] = keep + __shfl_xor(send, 1);
    }
    float U[4];
#pragma unroll
    for (int i = 0; i < 4; ++i) {
      float keep = b1 ? T[2*i+1] : T[2*i];
      float send = b1 ? T[2*i]   : T[2*i+1];
      U[i] = keep + __shfl_xor(send, 2);
    }
    float V[2];
#pragma unroll
    for (int i = 0; i < 2; ++i) {
      float keep = b2 ? U[2*i+1] : U[2*i];
      float send = b2 ? U[2*i]   : U[2*i+1];
      V[i] = keep + __shfl_xor(send, 4);
    }
    float Wv;
    {
      float keep = b3 ? V[1] : V[0];
      float send = b3 ? V[0] : V[1];
      Wv = keep + __shfl_xor(send, 8);
    }
    Wv += __shfl_xor(Wv, 16);
    Wv += __shfl_xor(Wv, 32);

    t += BETA * (Wv - cacc);             // t_{k+1} = t_k + beta*(G w - c)
  }

  // ---- epilogue: canonical lanes write x slice ----
  if (lane < 16) out[(size_t)batch * NDIM + i_own] = x;
}

extern "C" void kernel_launch(void* const* d_in, const int* in_sizes, int n_in,
                              void* d_out, int out_size, void* d_ws, size_t ws_size,
                              hipStream_t stream) {
  const float* A = (const float*)d_in[0];
  const float* b = (const float*)d_in[1];
  float* out  = (float*)d_out;
  float* slab = (float*)d_ws;                    // 128 KiB w-exchange slab

  hipMemsetAsync(d_ws, 0, SLAB_FL * sizeof(float), stream);  // tag 0 != 1,2

  void* args[] = {(void*)&A, (void*)&b, (void*)&out, (void*)&slab};
  hipLaunchCooperativeKernel((const void*)pdhg_kernel, dim3(NWG), dim3(BLK),
                             args, 0, stream);
}

// Round 10
// 1525.246 us; speedup vs baseline: 1.5453x; 1.5453x over previous
//
#include <hip/hip_runtime.h>

#define BS    32
#define MDIM  256
#define NDIM  512
#define ITERS 1000
#define BLK   512
#define NWG   128
#define ALPHA 0.02f
#define BETA  0.02f

// R10: stage-free iteration. Wave widx's G-columns = [64*widx, +64) = exactly
// the words its own lanes poll (thread polls word tid, proven layout) -> the
// w-fragment lives in the wave's registers; 8 independent __shfl replace the
// {LDS stage -> barrier -> LDS read} block. 3-stage halving butterfly (half
// of R3's dep chain) -> LDS partials [128][12] -> ONE barrier -> owners
// (tid&3==0, spread over all 8 waves: every wave's stores gate the tags --
// same parity/overwrite proof as baseline/R3) reduce 8, update t/x/w, store.
// Protocol byte-identical to the proven one (mantissa tags, 2-parity slab,
// agent-scope relaxed atomics, dependent spin -- R9 closed the book on
// exotic poll flavors).

// ---- LDS (floats) ----
#define ATS      520                 // prologue A-tile [32][520] + b[32]
#define BT_OFF   (32 * ATS)          // 16640
#define C_OFF    (BT_OFF + 32)       // c slice [128]
#define P_OFF    0                   // iteration partials [128][12] reuse A-tile
#define PSTRIDE  12                  // 48B rows: float4-aligned, conflict-light
#define SMEM_FL  21504               // 86016 B -> 1 wg/CU (baseline-proven)

// Exchange slab: [2 parity][BS][512] floats, mantissa-tagged (low 8 bits =
// (k+1)&255): every word self-validates. Tag-gating bounds drift <2 iters;
// owners in every wave => a wave stores k+1 only after its owners finished
// iter-k partial reads => poll k+1 passing implies all 32 waves done with k.
#define SLAB_FL  (2 * BS * NDIM)

__device__ __forceinline__ unsigned ld_coh_u32(const void* p) {
  return __hip_atomic_load(reinterpret_cast<const unsigned*>(p),
                           __ATOMIC_RELAXED, __HIP_MEMORY_SCOPE_AGENT);
}
__device__ __forceinline__ void st_coh_u32(void* p, unsigned v) {
  __hip_atomic_store(reinterpret_cast<unsigned*>(p), v,
                     __ATOMIC_RELAXED, __HIP_MEMORY_SCOPE_AGENT);
}
__device__ __forceinline__ unsigned tagf(float v, unsigned tag) {
  return (__float_as_uint(v) & ~0xFFu) | tag;
}

__global__ __launch_bounds__(BLK, 1) void pdhg_kernel(
    const float* __restrict__ A, const float* __restrict__ Bvec,
    float* __restrict__ out, float* __restrict__ slab)
{
  __shared__ float smem[SMEM_FL];
  const int tid   = threadIdx.x;
  const int bid   = blockIdx.x;
  const int batch = bid & (BS - 1);    // XCD-local mapping (proven best)
  const int slice = bid >> 5;          // wg owns G-rows [128*slice, +128)
  const int lane  = tid & 63;
  const int widx  = tid >> 6;          // wave's cols = [64*widx, +64)
  const int rg    = lane >> 3;         // row group: rows [16*rg, +16) (local)
  const int cg    = lane & 7;          // col group: cols 64*widx + 8*cg + [0,8)

  const int ibase = 128 * slice + 16 * rg;   // global row base of acc
  const int jbase = 64 * widx + 8 * cg;      // global col base of acc

  // ================= PROLOGUE: G tile in regs, c = A^T b ===================
  float acc[16][8];                    // acc[r][c] = G[ibase+r][jbase+c]
#pragma unroll
  for (int r = 0; r < 16; ++r)
#pragma unroll
    for (int c = 0; c < 8; ++c) acc[r][c] = 0.f;
  float cacc = 0.f;                    // tid<128: c[128*slice + tid]

  const float* Ag = A + (size_t)batch * MDIM * NDIM;

  for (int mt = 0; mt < MDIM / 32; ++mt) {
    // stage A[mt*32..+32, :] as [32][ATS] (baseline-verbatim, coalesced)
#pragma unroll 4
    for (int q = 0; q < 8; ++q) {
      int f  = q * 512 + tid;          // float4 index in 32x512 tile
      int mm = f >> 7;
      int j  = (f & 127) << 2;
      float4 v = *reinterpret_cast<const float4*>(
          Ag + (size_t)(mt * 32 + mm) * NDIM + j);
      *reinterpret_cast<float4*>(&smem[mm * ATS + j]) = v;
    }
    if (tid < 32) smem[BT_OFF + tid] = Bvec[batch * MDIM + mt * 32 + tid];
    __syncthreads();

#pragma unroll 2
    for (int m = 0; m < 32; ++m) {
      const float* row = &smem[m * ATS];
      // ai[16]: 4x float4, 8-way broadcast over cg -> free
      float4 a0 = *reinterpret_cast<const float4*>(row + ibase);
      float4 a1 = *reinterpret_cast<const float4*>(row + ibase + 4);
      float4 a2 = *reinterpret_cast<const float4*>(row + ibase + 8);
      float4 a3 = *reinterpret_cast<const float4*>(row + ibase + 12);
      float ai[16] = {a0.x,a0.y,a0.z,a0.w, a1.x,a1.y,a1.z,a1.w,
                      a2.x,a2.y,a2.z,a2.w, a3.x,a3.y,a3.z,a3.w};
      // aj[8]: 2x float4, 8-way broadcast over rg
      float4 j0 = *reinterpret_cast<const float4*>(row + jbase);
      float4 j1 = *reinterpret_cast<const float4*>(row + jbase + 4);
      float aj[8] = {j0.x,j0.y,j0.z,j0.w, j1.x,j1.y,j1.z,j1.w};
      float bm = smem[BT_OFF + m];
#pragma unroll
      for (int r = 0; r < 16; ++r)
#pragma unroll
        for (int c = 0; c < 8; ++c) acc[r][c] = fmaf(ai[r], aj[c], acc[r][c]);
      if (tid < 128) cacc = fmaf(row[128 * slice + tid], bm, cacc);
    }
    __syncthreads();
  }
  if (tid < 128) smem[C_OFF + tid] = cacc;
  __syncthreads();

  // ================= ITERATION ============================================
  const bool owner = (tid & 3) == 0;
  const int  Rloc  = tid >> 2;                 // owner's local row 0..127
  const float c_reg = owner ? smem[C_OFF + Rloc] : 0.f;
  float x = 0.f, t = 0.f;

  float*       myslot = slab + batch * NDIM + 128 * slice + Rloc;  // +parity
  const float* myrd   = slab + batch * NDIM + tid;   // coalesced poll: word tid

  for (int k = 0; k < ITERS; ++k) {
    float xn = 0.f;
    if (owner) {
      float y = x - ALPHA * t;
      xn = fmaxf(y - ALPHA, 0.f) - fmaxf(-y - ALPHA, 0.f);
    }
    if (k == ITERS - 1) { x = xn; break; }

    const int      par = (k & 1) * BS * NDIM;
    const unsigned tag = (unsigned)(k + 1) & 0xFFu;
    if (owner) {
      float wv_ = 2.f * xn - x;
      x = xn;
      st_coh_u32(myslot + par, tagf(wv_, tag));
    }

    // poll own word (self-validating mantissa tag; proven dependent spin)
    unsigned q;
    do { q = ld_coh_u32(myrd + par); } while ((q ^ tag) & 0xFFu);
    float w_own = __uint_as_float(q);

    // w gather: lane's 8 cols live in lanes 8*cg..8*cg+7 of THIS wave
    float wv[8];
#pragma unroll
    for (int c = 0; c < 8; ++c) wv[c] = __shfl(w_own, 8 * cg + c);

    float S[16];
#pragma unroll
    for (int r = 0; r < 16; ++r) {
      float p = acc[r][0] * wv[0];
#pragma unroll
      for (int c = 1; c < 8; ++c) p = fmaf(acc[r][c], wv[c], p);
      S[r] = p;
    }

    // 3-stage value-halving butterfly over cg bits (R3-verified pattern,
    // stages 1,2,4): V[i] = full-wave sum for local row 16*rg + 8*i + cg.
    const bool b0 = (lane & 1), b1 = (lane & 2), b2 = (lane & 4);
    float T[8];
#pragma unroll
    for (int i = 0; i < 8; ++i) {
      float keep = b0 ? S[2*i+1] : S[2*i];
      float send = b0 ? S[2*i]   : S[2*i+1];
      T[i] = keep + __shfl_xor(send, 1);
    }
    float U[4];
#pragma unroll
    for (int i = 0; i < 4; ++i) {
      float keep = b1 ? T[2*i+1] : T[2*i];
      float send = b1 ? T[2*i]   : T[2*i+1];
      U[i] = keep + __shfl_xor(send, 2);
    }
    float V[2];
#pragma unroll
    for (int i = 0; i < 2; ++i) {
      float keep = b2 ? U[2*i+1] : U[2*i];
      float send = b2 ? U[2*i]   : U[2*i+1];
      V[i] = keep + __shfl_xor(send, 4);
    }

    // wave-partials -> LDS [128][12]; one barrier; owners reduce 8.
    smem[P_OFF + (16 * rg + cg)     * PSTRIDE + widx] = V[0];
    smem[P_OFF + (16 * rg + 8 + cg) * PSTRIDE + widx] = V[1];
    __syncthreads();

    if (owner) {
      const float* pp = &smem[P_OFF + Rloc * PSTRIDE];   // 48B-aligned
      float4 pa = *reinterpret_cast<const float4*>(pp);
      float4 pb = *reinterpret_cast<const float4*>(pp + 4);
      float s8 = (pa.x + pa.y) + (pa.z + pa.w) +
                 (pb.x + pb.y) + (pb.z + pb.w);
      t += BETA * (s8 - c_reg);          // t_{k+1} = t_k + beta*(Gw - c)
    }
  }

  // ---- epilogue: owners write x slice ----
  if (owner) out[(size_t)batch * NDIM + 128 * slice + Rloc] = x;
}

extern "C" void kernel_launch(void* const* d_in, const int* in_sizes, int n_in,
                              void* d_out, int out_size, void* d_ws, size_t ws_size,
                              hipStream_t stream) {
  const float* A = (const float*)d_in[0];
  const float* b = (const float*)d_in[1];
  float* out  = (float*)d_out;
  float* slab = (float*)d_ws;                    // 128 KiB w-exchange slab

  hipMemsetAsync(d_ws, 0, SLAB_FL * sizeof(float), stream);  // tag 0 != 1,2

  void* args[] = {(void*)&A, (void*)&b, (void*)&out, (void*)&slab};
  hipLaunchCooperativeKernel((const void*)pdhg_kernel, dim3(NWG), dim3(BLK),
                             args, 0, stream);
}

// Round 11
// 1508.242 us; speedup vs baseline: 1.5627x; 1.0113x over previous
//
#include <hip/hip_runtime.h>

#define BS    32
#define MDIM  256
#define NDIM  512
#define ITERS 1000
#define BLK   512
#define NWG   128
#define ALPHA 0.02f
#define BETA  0.02f

// R11 = R10 + write-side XOR swizzle on the V-partials (R10's one failed
// sub-prediction: 2.86e7 bank conflicts, all from the V writes — bank =
// (192rg + 12cg + widx) mod 32 and 192 == 0 mod 32 -> 8-way over rg).
// Swizzled column (widx ^ rg): bank = (12cg + (widx^rg)) mod 32 -> exactly
// 2 lanes/bank = free (m136). Owner sums all 8 columns of its row and
// p -> p^rg is a bijection for fixed rg (rg = row>>4 fixed per row) -> the
// owner code is UNCHANGED; one owner per row -> no consistency concern.
// Everything else byte-identical to R10 (first sub-baseline kernel: 1525us).

// ---- LDS (floats) ----
#define ATS      520                 // prologue A-tile [32][520] + b[32]
#define BT_OFF   (32 * ATS)          // 16640
#define C_OFF    (BT_OFF + 32)       // c slice [128]
#define P_OFF    0                   // iteration partials [128][12] reuse A-tile
#define PSTRIDE  12                  // 48B rows: float4-aligned
#define SMEM_FL  21504               // 86016 B -> 1 wg/CU (baseline-proven)

// Exchange slab: [2 parity][BS][512] floats, mantissa-tagged (low 8 bits =
// (k+1)&255): every word self-validates. Tag-gating bounds drift <2 iters;
// owners in every wave => a wave stores k+1 only after its owners finished
// iter-k partial reads => poll k+1 passing implies all 32 waves done with k.
#define SLAB_FL  (2 * BS * NDIM)

__device__ __forceinline__ unsigned ld_coh_u32(const void* p) {
  return __hip_atomic_load(reinterpret_cast<const unsigned*>(p),
                           __ATOMIC_RELAXED, __HIP_MEMORY_SCOPE_AGENT);
}
__device__ __forceinline__ void st_coh_u32(void* p, unsigned v) {
  __hip_atomic_store(reinterpret_cast<unsigned*>(p), v,
                     __ATOMIC_RELAXED, __HIP_MEMORY_SCOPE_AGENT);
}
__device__ __forceinline__ unsigned tagf(float v, unsigned tag) {
  return (__float_as_uint(v) & ~0xFFu) | tag;
}

__global__ __launch_bounds__(BLK, 1) void pdhg_kernel(
    const float* __restrict__ A, const float* __restrict__ Bvec,
    float* __restrict__ out, float* __restrict__ slab)
{
  __shared__ float smem[SMEM_FL];
  const int tid   = threadIdx.x;
  const int bid   = blockIdx.x;
  const int batch = bid & (BS - 1);    // XCD-local mapping (proven best)
  const int slice = bid >> 5;          // wg owns G-rows [128*slice, +128)
  const int lane  = tid & 63;
  const int widx  = tid >> 6;          // wave's cols = [64*widx, +64)
  const int rg    = lane >> 3;         // row group: rows [16*rg, +16) (local)
  const int cg    = lane & 7;          // col group: cols 64*widx + 8*cg + [0,8)

  const int ibase = 128 * slice + 16 * rg;   // global row base of acc
  const int jbase = 64 * widx + 8 * cg;      // global col base of acc

  // ================= PROLOGUE: G tile in regs, c = A^T b ===================
  float acc[16][8];                    // acc[r][c] = G[ibase+r][jbase+c]
#pragma unroll
  for (int r = 0; r < 16; ++r)
#pragma unroll
    for (int c = 0; c < 8; ++c) acc[r][c] = 0.f;
  float cacc = 0.f;                    // tid<128: c[128*slice + tid]

  const float* Ag = A + (size_t)batch * MDIM * NDIM;

  for (int mt = 0; mt < MDIM / 32; ++mt) {
    // stage A[mt*32..+32, :] as [32][ATS] (baseline-verbatim, coalesced)
#pragma unroll 4
    for (int q = 0; q < 8; ++q) {
      int f  = q * 512 + tid;          // float4 index in 32x512 tile
      int mm = f >> 7;
      int j  = (f & 127) << 2;
      float4 v = *reinterpret_cast<const float4*>(
          Ag + (size_t)(mt * 32 + mm) * NDIM + j);
      *reinterpret_cast<float4*>(&smem[mm * ATS + j]) = v;
    }
    if (tid < 32) smem[BT_OFF + tid] = Bvec[batch * MDIM + mt * 32 + tid];
    __syncthreads();

#pragma unroll 2
    for (int m = 0; m < 32; ++m) {
      const float* row = &smem[m * ATS];
      // ai[16]: 4x float4, 8-way broadcast over cg -> free
      float4 a0 = *reinterpret_cast<const float4*>(row + ibase);
      float4 a1 = *reinterpret_cast<const float4*>(row + ibase + 4);
      float4 a2 = *reinterpret_cast<const float4*>(row + ibase + 8);
      float4 a3 = *reinterpret_cast<const float4*>(row + ibase + 12);
      float ai[16] = {a0.x,a0.y,a0.z,a0.w, a1.x,a1.y,a1.z,a1.w,
                      a2.x,a2.y,a2.z,a2.w, a3.x,a3.y,a3.z,a3.w};
      // aj[8]: 2x float4, 8-way broadcast over rg
      float4 j0 = *reinterpret_cast<const float4*>(row + jbase);
      float4 j1 = *reinterpret_cast<const float4*>(row + jbase + 4);
      float aj[8] = {j0.x,j0.y,j0.z,j0.w, j1.x,j1.y,j1.z,j1.w};
      float bm = smem[BT_OFF + m];
#pragma unroll
      for (int r = 0; r < 16; ++r)
#pragma unroll
        for (int c = 0; c < 8; ++c) acc[r][c] = fmaf(ai[r], aj[c], acc[r][c]);
      if (tid < 128) cacc = fmaf(row[128 * slice + tid], bm, cacc);
    }
    __syncthreads();
  }
  if (tid < 128) smem[C_OFF + tid] = cacc;
  __syncthreads();

  // ================= ITERATION ============================================
  const bool owner = (tid & 3) == 0;
  const int  Rloc  = tid >> 2;                 // owner's local row 0..127
  const float c_reg = owner ? smem[C_OFF + Rloc] : 0.f;
  float x = 0.f, t = 0.f;

  float*       myslot = slab + batch * NDIM + 128 * slice + Rloc;  // +parity
  const float* myrd   = slab + batch * NDIM + tid;   // coalesced poll: word tid

  const int swzcol = widx ^ rg;        // bank-free partials column (R11)

  for (int k = 0; k < ITERS; ++k) {
    float xn = 0.f;
    if (owner) {
      float y = x - ALPHA * t;
      xn = fmaxf(y - ALPHA, 0.f) - fmaxf(-y - ALPHA, 0.f);
    }
    if (k == ITERS - 1) { x = xn; break; }

    const int      par = (k & 1) * BS * NDIM;
    const unsigned tag = (unsigned)(k + 1) & 0xFFu;
    if (owner) {
      float wv_ = 2.f * xn - x;
      x = xn;
      st_coh_u32(myslot + par, tagf(wv_, tag));
    }

    // poll own word (self-validating mantissa tag; proven dependent spin)
    unsigned q;
    do { q = ld_coh_u32(myrd + par); } while ((q ^ tag) & 0xFFu);
    float w_own = __uint_as_float(q);

    // w gather: lane's 8 cols live in lanes 8*cg..8*cg+7 of THIS wave
    float wv[8];
#pragma unroll
    for (int c = 0; c < 8; ++c) wv[c] = __shfl(w_own, 8 * cg + c);

    float S[16];
#pragma unroll
    for (int r = 0; r < 16; ++r) {
      float p = acc[r][0] * wv[0];
#pragma unroll
      for (int c = 1; c < 8; ++c) p = fmaf(acc[r][c], wv[c], p);
      S[r] = p;
    }

    // 3-stage value-halving butterfly over cg bits (R3-verified pattern,
    // stages 1,2,4): V[i] = full-wave sum for local row 16*rg + 8*i + cg.
    const bool b0 = (lane & 1), b1 = (lane & 2), b2 = (lane & 4);
    float T[8];
#pragma unroll
    for (int i = 0; i < 8; ++i) {
      float keep = b0 ? S[2*i+1] : S[2*i];
      float send = b0 ? S[2*i]   : S[2*i+1];
      T[i] = keep + __shfl_xor(send, 1);
    }
    float U[4];
#pragma unroll
    for (int i = 0; i < 4; ++i) {
      float keep = b1 ? T[2*i+1] : T[2*i];
      float send = b1 ? T[2*i]   : T[2*i+1];
      U[i] = keep + __shfl_xor(send, 2);
    }
    float V[2];
#pragma unroll
    for (int i = 0; i < 2; ++i) {
      float keep = b2 ? U[2*i+1] : U[2*i];
      float send = b2 ? U[2*i]   : U[2*i+1];
      V[i] = keep + __shfl_xor(send, 4);
    }

    // wave-partials -> LDS [128][12] at swizzled column widx^rg: bank =
    // (12cg + widx^rg) mod 32 -> exactly 2 lanes/bank (free). Owner sums
    // all 8 columns of its row; the per-row bijection is invisible to it.
    smem[P_OFF + (16 * rg + cg)     * PSTRIDE + swzcol] = V[0];
    smem[P_OFF + (16 * rg + 8 + cg) * PSTRIDE + swzcol] = V[1];
    __syncthreads();

    if (owner) {
      const float* pp = &smem[P_OFF + Rloc * PSTRIDE];   // 2-way banks: free
      float4 pa = *reinterpret_cast<const float4*>(pp);
      float4 pb = *reinterpret_cast<const float4*>(pp + 4);
      float s8 = (pa.x + pa.y) + (pa.z + pa.w) +
                 (pb.x + pb.y) + (pb.z + pb.w);
      t += BETA * (s8 - c_reg);          // t_{k+1} = t_k + beta*(Gw - c)
    }
  }

  // ---- epilogue: owners write x slice ----
  if (owner) out[(size_t)batch * NDIM + 128 * slice + Rloc] = x;
}

extern "C" void kernel_launch(void* const* d_in, const int* in_sizes, int n_in,
                              void* d_out, int out_size, void* d_ws, size_t ws_size,
                              hipStream_t stream) {
  const float* A = (const float*)d_in[0];
  const float* b = (const float*)d_in[1];
  float* out  = (float*)d_out;
  float* slab = (float*)d_ws;                    // 128 KiB w-exchange slab

  hipMemsetAsync(d_ws, 0, SLAB_FL * sizeof(float), stream);  // tag 0 != 1,2

  void* args[] = {(void*)&A, (void*)&b, (void*)&out, (void*)&slab};
  hipLaunchCooperativeKernel((const void*)pdhg_kernel, dim3(NWG), dim3(BLK),
                             args, 0, stream);
}